// Round 12
// baseline (595.446 us; speedup 1.0000x reference)
//
#include <hip/hip_runtime.h>
#include <hip/hip_bf16.h>

#define NR 8192
#define WF 128
#define MSTRIDE 260   // mask LDS row stride in u32 (260%32=4 -> 2-way bank = free)

typedef short bf16x8 __attribute__((ext_vector_type(8)));
typedef float f32x4 __attribute__((ext_vector_type(4)));
typedef int   i32x4 __attribute__((ext_vector_type(4)));

static __device__ __forceinline__ unsigned int f2bf(float f) {
    unsigned int u = __float_as_uint(f);
    return (u + 0x7fffu + ((u >> 16) & 1u)) >> 16;
}
// works with *addr initialized to 0xFFFFFFFF (-NaN): int-max beats -1 for v>=0,
// uint-min beats UINT_MAX for v<0; mixed-sign interleavings keep the true max.
static __device__ __forceinline__ void atomicMaxF(float* addr, float v) {
    if (v >= 0.f) atomicMax((int*)addr, __float_as_int(v));
    else          atomicMin((unsigned int*)addr, __float_as_uint(v));
}
static __device__ __forceinline__ float lrelu(float x) { return x > 0.f ? x : 0.01f * x; }

// ---- k_proj: h = emb[inSen] @ W ; f_src/f_dst ; maxfd (atomic) ; hB (bf16 B-frags) ----
// hB layout: [colblk kb (256)][featgrp nf (8)][lane (64)][8 bf16]; lane = fx + 16*quad
// holds h^T[nf*16+fx][kb*32 + quad*8 + j], j=0..7.  Block = 16 rows (half a colblk).
__global__ __launch_bounds__(256) void k_proj(
    const int* __restrict__ inSen, const float* __restrict__ emb,
    const float* __restrict__ W, const float* __restrict__ a_src,
    const float* __restrict__ a_dst, float* __restrict__ f_src,
    float* __restrict__ f_dst, float* __restrict__ maxfd,
    unsigned short* __restrict__ hB)
{
    __shared__ float ht[16 * 132];
    const int t = threadIdx.x;
    const int f = t & 127, rh = t >> 7;     // feature, row-half (8 rows each)
    const int i0 = blockIdx.x * 16;

    int wd[8];
    #pragma unroll
    for (int r = 0; r < 8; ++r) wd[r] = inSen[i0 + rh * 8 + r];
    float h[8];
    #pragma unroll
    for (int r = 0; r < 8; ++r) h[r] = 0.f;

    for (int k4 = 0; k4 < 32; ++k4) {
        const float w0 = W[(k4 * 4 + 0) * WF + f];
        const float w1 = W[(k4 * 4 + 1) * WF + f];
        const float w2 = W[(k4 * 4 + 2) * WF + f];
        const float w3 = W[(k4 * 4 + 3) * WF + f];
        #pragma unroll
        for (int r = 0; r < 8; ++r) {
            float4 ev = ((const float4*)(emb + (size_t)wd[r] * 128))[k4];
            h[r] += ev.x * w0 + ev.y * w1 + ev.z * w2 + ev.w * w3;
        }
    }
    #pragma unroll
    for (int r = 0; r < 8; ++r) ht[(rh * 8 + r) * 132 + f] = h[r];
    __syncthreads();

    if (t < 16) {
        float s = 0.f, d = 0.f;
        for (int k4 = 0; k4 < 32; ++k4) {
            float4 hv = *(const float4*)(ht + t * 132 + k4 * 4);
            float4 as = ((const float4*)a_src)[k4];
            float4 ad = ((const float4*)a_dst)[k4];
            s += hv.x * as.x + hv.y * as.y + hv.z * as.z + hv.w * as.w;
            d += hv.x * ad.x + hv.y * ad.y + hv.z * ad.z + hv.w * ad.w;
        }
        f_src[i0 + t] = s;
        f_dst[i0 + t] = d;
        float dm = d;
        #pragma unroll
        for (int o = 1; o < 16; o <<= 1) dm = fmaxf(dm, __shfl_xor(dm, o));
        if (t == 0) atomicMaxF(maxfd, dm);
    }
    // hB fragment write: this block fills quads {half*2, half*2+1} of colblk kb
    {
        const int kb = blockIdx.x >> 1, half = blockIdx.x & 1;
        const int nf = t >> 5, l32 = t & 31;
        const int qloc = l32 >> 4, fx = l32 & 15;
        const int lane = (half * 2 + qloc) * 16 + fx;
        const float* hp = ht + (qloc * 8) * 132 + nf * 16 + fx;
        uint4 v;
        v.x = f2bf(hp[0 * 132]) | (f2bf(hp[1 * 132]) << 16);
        v.y = f2bf(hp[2 * 132]) | (f2bf(hp[3 * 132]) << 16);
        v.z = f2bf(hp[4 * 132]) | (f2bf(hp[5 * 132]) << 16);
        v.w = f2bf(hp[6 * 132]) | (f2bf(hp[7 * 132]) << 16);
        *(uint4*)(hB + ((size_t)kb * 8 + nf) * 512 + lane * 8) = v;
    }
}

// ---- adj chunk: 256 cols, lane owns 4 (i32x4, NT-loaded). Mask word -> mrow (LDS). ----
static __device__ __forceinline__ void adj_chunk(
    int c, i32x4 a, const float* __restrict__ fdl, int lane, int row, int sl,
    float fs, float C, int shl,
    unsigned int* __restrict__ mrow, float& sum)
{
    const float4 f = *(const float4*)(fdl + c * 256 + 4 * lane);
    const bool m0 = a[0] > 0, m1 = a[1] > 0, m2 = a[2] > 0, m3 = a[3] > 0;
    float p0 = m0 ? __expf(lrelu(fs + f.x) - C) : 0.f;
    float p1 = m1 ? __expf(lrelu(fs + f.y) - C) : 0.f;
    float p2 = m2 ? __expf(lrelu(fs + f.z) - C) : 0.f;
    float p3 = m3 ? __expf(lrelu(fs + f.w) - C) : 0.f;
    unsigned int nib = (m0 ? 1u : 0u) | (m1 ? 2u : 0u) | (m2 ? 4u : 0u) | (m3 ? 8u : 0u);
    float ssum = p0 + p1 + p2 + p3;
    if (c == (row >> 8)) {                      // wave-uniform: diagonal lives here
        if (lane == ((row & 255) >> 2)) {
            const int jd = row & 3;
            const int aj = jd == 0 ? a[0] : jd == 1 ? a[1] : jd == 2 ? a[2] : a[3];
            const float fj = jd == 0 ? f.x : jd == 1 ? f.y : jd == 2 ? f.z : f.w;
            const bool mo = aj > 0, mn = (aj + sl) > 0;
            if (mn != mo) {
                const float pd = __expf(lrelu(fs + fj) - C);
                if (mn) { nib |= 1u << jd; ssum += pd; }
                else    { nib &= ~(1u << jd); ssum -= pd; }
            }
        }
    }
    sum += ssum;
    // pack 8 lanes' nibbles -> one u32 mask word (bit = col%32), 8 words per 256-col chunk
    unsigned int v = nib << shl;
    v |= __shfl_xor(v, 1);
    v |= __shfl_xor(v, 2);
    v |= __shfl_xor(v, 4);
    if ((lane & 7) == 0) mrow[c * 8 + (lane >> 3)] = v;
}

#define NTL(p) __builtin_nontemporal_load((const i32x4*)(p))

// ---- k_fused v7: v6 + (a) phase-1 DUAL-ROW interleaved scan (two independent dep
// chains per wave, no mid-phase ring drain; depth-4 x 2 rows = same registers as
// depth-8 x 1), (b) phase-2 bf16 pack via v_cvt_pk (float2 cast; RNE == old f2bf),
// (c) att stores batched per 2 iterations (stores share in-order vmcnt with loads;
// pair-end stores get ~1.5 iters of drain slack before the next MFMA's vmcnt wait).
__global__ __launch_bounds__(1024, 4) void k_fused(
    const int* __restrict__ adj, const int* __restrict__ slP,
    const float* __restrict__ f_src, const float* __restrict__ f_dst,
    const float* __restrict__ maxfd, const unsigned short* __restrict__ hB,
    float* __restrict__ att, float* __restrict__ sent, float* __restrict__ partial)
{
    __shared__ float fdl[NR];                                    // 32 KB
    __shared__ __align__(16) unsigned int mask[32 * MSTRIDE];    // 33.3 KB
    __shared__ float sums[32];
    const int t = threadIdx.x, lane = t & 63, w = t >> 6;   // 16 waves
    const int i0 = blockIdx.x * 32;                          // 32 rows per block

    // issue BOTH rows' adj rings FIRST (HBM latency hides under fdl stage + barrier)
    const int rowA = i0 + 2 * w, rowB = rowA + 1;
    const int* __restrict__ apA = adj + (size_t)rowA * NR + 4 * lane;
    const int* __restrict__ apB = adj + (size_t)rowB * NR + 4 * lane;
    i32x4 A0 = NTL(apA + 0 * 256);
    i32x4 A1 = NTL(apA + 1 * 256);
    i32x4 A2 = NTL(apA + 2 * 256);
    i32x4 A3 = NTL(apA + 3 * 256);
    i32x4 B0 = NTL(apB + 0 * 256);
    i32x4 B1 = NTL(apB + 1 * 256);
    i32x4 B2 = NTL(apB + 2 * 256);
    i32x4 B3 = NTL(apB + 3 * 256);

    #pragma unroll
    for (int i = 0; i < 2; ++i)
        *(float4*)(fdl + (i * 1024 + t) * 4) = *(const float4*)(f_dst + (i * 1024 + t) * 4);

    const int sl = slP[0];
    const float mfd = maxfd[0];
    const int shl = 4 * (lane & 7);
    __syncthreads();

    // ---- phase 1: dual-row interleaved scan (rows 2w, 2w+1) ----
    {
        const float fsA = f_src[rowA], CA = lrelu(fsA + mfd);
        const float fsB = f_src[rowB], CB = lrelu(fsB + mfd);
        unsigned int* __restrict__ mrA = mask + (2 * w) * MSTRIDE;
        unsigned int* __restrict__ mrB = mask + (2 * w + 1) * MSTRIDE;
        float sA = 0.f, sB = 0.f;
        #define ADJA(c, reg) adj_chunk((c), (reg), fdl, lane, rowA, sl, fsA, CA, shl, mrA, sA)
        #define ADJB(c, reg) adj_chunk((c), (reg), fdl, lane, rowB, sl, fsB, CB, shl, mrB, sB)
        #pragma unroll 1
        for (int g = 0; g < 28; g += 4) {
            ADJA(g + 0, A0); A0 = NTL(apA + (g + 4) * 256);
            ADJB(g + 0, B0); B0 = NTL(apB + (g + 4) * 256);
            ADJA(g + 1, A1); A1 = NTL(apA + (g + 5) * 256);
            ADJB(g + 1, B1); B1 = NTL(apB + (g + 5) * 256);
            ADJA(g + 2, A2); A2 = NTL(apA + (g + 6) * 256);
            ADJB(g + 2, B2); B2 = NTL(apB + (g + 6) * 256);
            ADJA(g + 3, A3); A3 = NTL(apA + (g + 7) * 256);
            ADJB(g + 3, B3); B3 = NTL(apB + (g + 7) * 256);
        }
        ADJA(28, A0); ADJB(28, B0);
        ADJA(29, A1); ADJB(29, B1);
        ADJA(30, A2); ADJB(30, B2);
        ADJA(31, A3); ADJB(31, B3);
        #undef ADJA
        #undef ADJB
        #pragma unroll
        for (int o = 1; o < 64; o <<= 1) {
            sA += __shfl_xor(sA, o);
            sB += __shfl_xor(sB, o);
        }
        if (lane == 0) { sums[2 * w] = 1.0f / sA; sums[2 * w + 1] = 1.0f / sB; }
    }
    __syncthreads();

    // ---- phase 2: waves 0-7 -> strip 0, waves 8-15 -> strip 1; wave pair (w, w+8)
    // shares the same hB K-slice. Pair-batched stores + cvt_pk bf16 packing.
    const int ss = w >> 3, wk = w & 7;
    const int fx = lane & 15, quad = lane >> 4;
    const int lrow = ss * 16 + fx;
    const int row = i0 + lrow;
    const float fs = f_src[row];
    const float C = lrelu(fs + mfd);
    const float il = sums[lrow];
    float* __restrict__ ar = att + (size_t)row * NR;
    const unsigned int* __restrict__ mrow = mask + lrow * MSTRIDE;
    f32x4 acc[8] = {};
    const int k0 = wk * 1024;

    for (int kk4 = k0; kk4 < k0 + 1024; kk4 += 128) {
        const uint4 mw = *(const uint4*)(mrow + (kk4 >> 5));     // LDS
        const unsigned int mwa[4] = {mw.x, mw.y, mw.z, mw.w};
        #pragma unroll
        for (int j2 = 0; j2 < 2; ++j2) {
            const int kkA = kk4 + (2 * j2) * 32;
            const int kkB = kkA + 32;
            float pA[8], pB[8];
            {   // --- iter A: loads, exp, pack, MFMA (no stores yet) ---
                const unsigned short* hp = hB + (size_t)(kkA >> 5) * 4096 + lane * 8;
                bf16x8 bfr[8];
                #pragma unroll
                for (int nf = 0; nf < 8; ++nf) bfr[nf] = *(const bf16x8*)(hp + nf * 512);
                const unsigned int mbyte = (mwa[2 * j2] >> (quad * 8)) & 0xffu;
                const float4 fd0 = *(const float4*)(fdl + kkA + quad * 8);
                const float4 fd1 = *(const float4*)(fdl + kkA + quad * 8 + 4);
                const float fv[8] = {fd0.x, fd0.y, fd0.z, fd0.w, fd1.x, fd1.y, fd1.z, fd1.w};
                #pragma unroll
                for (int j = 0; j < 8; ++j)
                    pA[j] = ((mbyte >> j) & 1u) ? __expf(lrelu(fs + fv[j]) - C) : 0.f;
                union { __hip_bfloat162 h2[4]; bf16x8 v; } cv;
                #pragma unroll
                for (int j = 0; j < 4; ++j)
                    cv.h2[j] = __float22bfloat162_rn(make_float2(pA[2 * j], pA[2 * j + 1]));
                #pragma unroll
                for (int nf = 0; nf < 8; ++nf)
                    acc[nf] = __builtin_amdgcn_mfma_f32_16x16x32_bf16(cv.v, bfr[nf], acc[nf], 0, 0, 0);
            }
            {   // --- iter B ---
                const unsigned short* hp = hB + (size_t)(kkB >> 5) * 4096 + lane * 8;
                bf16x8 bfr[8];
                #pragma unroll
                for (int nf = 0; nf < 8; ++nf) bfr[nf] = *(const bf16x8*)(hp + nf * 512);
                const unsigned int mbyte = (mwa[2 * j2 + 1] >> (quad * 8)) & 0xffu;
                const float4 fd0 = *(const float4*)(fdl + kkB + quad * 8);
                const float4 fd1 = *(const float4*)(fdl + kkB + quad * 8 + 4);
                const float fv[8] = {fd0.x, fd0.y, fd0.z, fd0.w, fd1.x, fd1.y, fd1.z, fd1.w};
                #pragma unroll
                for (int j = 0; j < 8; ++j)
                    pB[j] = ((mbyte >> j) & 1u) ? __expf(lrelu(fs + fv[j]) - C) : 0.f;
                union { __hip_bfloat162 h2[4]; bf16x8 v; } cv;
                #pragma unroll
                for (int j = 0; j < 4; ++j)
                    cv.h2[j] = __float22bfloat162_rn(make_float2(pB[2 * j], pB[2 * j + 1]));
                #pragma unroll
                for (int nf = 0; nf < 8; ++nf)
                    acc[nf] = __builtin_amdgcn_mfma_f32_16x16x32_bf16(cv.v, bfr[nf], acc[nf], 0, 0, 0);
            }
            // --- pair-end att stores (normal L2 stores; w0/w1 interleave needs merge) ---
            *(float4*)(ar + kkA + quad * 8) =
                make_float4(pA[0] * il, pA[1] * il, pA[2] * il, pA[3] * il);
            *(float4*)(ar + kkA + quad * 8 + 4) =
                make_float4(pA[4] * il, pA[5] * il, pA[6] * il, pA[7] * il);
            *(float4*)(ar + kkB + quad * 8) =
                make_float4(pB[0] * il, pB[1] * il, pB[2] * il, pB[3] * il);
            *(float4*)(ar + kkB + quad * 8 + 4) =
                make_float4(pB[4] * il, pB[5] * il, pB[6] * il, pB[7] * il);
        }
    }
    // ---- epilogue: tile ALIASES mask (dead after K-loop). barrier-separated. ----
    __syncthreads();                          // all mask/fdl reads complete
    float* tile = (float*)mask;               // 2 strips x 2048 floats = 16 KB
    *(float4*)(tile + t * 4) = make_float4(0.f, 0.f, 0.f, 0.f);
    __syncthreads();
    // D layout (16x16x32): row = quad*4+reg, col = nf*16+fx
    #pragma unroll
    for (int reg = 0; reg < 4; ++reg) {
        #pragma unroll
        for (int nf = 0; nf < 8; ++nf)
            atomicAdd(&tile[ss * 2048 + (quad * 4 + reg) * 128 + nf * 16 + fx], acc[nf][reg]);
    }
    __syncthreads();
    {   // sent: 4096 floats, 1 float4/thread, scaled by invl
        const int e = t * 4;
        const int st2 = e >> 11, off = e & 2047, r = off >> 7, f0 = off & 127;
        const float vin = sums[st2 * 16 + r];
        float4 vv = make_float4(tile[e] * vin, tile[e + 1] * vin,
                                tile[e + 2] * vin, tile[e + 3] * vin);
        *(float4*)(sent + (size_t)(i0 + st2 * 16 + r) * WF + f0) = vv;
    }
    if (t < 128) {                            // column max over the block's 32 rows
        float mx = -1e30f;
        #pragma unroll
        for (int s = 0; s < 2; ++s)
            for (int r = 0; r < 16; ++r)
                mx = fmaxf(mx, tile[s * 2048 + r * 128 + t] * sums[s * 16 + r]);
        partial[blockIdx.x * 128 + t] = mx;
    }
}

// ---- k_label: final pool max (256 block partials) + classifier ------------------------
__global__ __launch_bounds__(128) void k_label(
    const float* __restrict__ partial, const float* __restrict__ cls_W,
    const float* __restrict__ cls_b, float* __restrict__ pool,
    float* __restrict__ label)
{
    __shared__ float s0[128], s1[128];
    const int t = threadIdx.x;
    float m0 = -1e30f, m1 = -1e30f, m2 = -1e30f, m3 = -1e30f;
    for (int b = 0; b < 256; b += 4) {
        m0 = fmaxf(m0, partial[(b + 0) * 128 + t]);
        m1 = fmaxf(m1, partial[(b + 1) * 128 + t]);
        m2 = fmaxf(m2, partial[(b + 2) * 128 + t]);
        m3 = fmaxf(m3, partial[(b + 3) * 128 + t]);
    }
    const float m = fmaxf(fmaxf(m0, m1), fmaxf(m2, m3));
    pool[t] = m;
    s0[t] = m * cls_W[t * 2 + 0];
    s1[t] = m * cls_W[t * 2 + 1];
    __syncthreads();
    if (t == 0) {
        float z0 = cls_b[0], z1 = cls_b[1];
        for (int f = 0; f < 128; ++f) { z0 += s0[f]; z1 += s1[f]; }
        float mm = fmaxf(z0, z1);
        float e0 = __expf(z0 - mm), e1 = __expf(z1 - mm);
        float inv = 1.0f / (e0 + e1);
        label[0] = e0 * inv;
        label[1] = e1 * inv;
    }
}

extern "C" void kernel_launch(void* const* d_in, const int* in_sizes, int n_in,
                              void* d_out, int out_size, void* d_ws, size_t ws_size,
                              hipStream_t stream)
{
    const int*   inSen    = (const int*)d_in[0];
    const int*   adj      = (const int*)d_in[1];
    const int*   selfLink = (const int*)d_in[2];
    const float* emb      = (const float*)d_in[3];
    const float* W        = (const float*)d_in[4];
    const float* a_src    = (const float*)d_in[5];
    const float* a_dst    = (const float*)d_in[6];
    const float* cls_W    = (const float*)d_in[7];
    const float* cls_b    = (const float*)d_in[8];

    float* out   = (float*)d_out;
    float* pool  = out;                         // 128
    float* att   = out + 128;                   // 8192*8192
    float* sent  = att + (size_t)NR * NR;       // 8192*128
    float* label = sent + (size_t)NR * WF;      // 2

    char* ws = (char*)d_ws;
    unsigned short* hB    = (unsigned short*)ws;               // 2 MB
    float* f_src   = (float*)(ws + (2u << 20));                // 32 KB
    float* f_dst   = f_src + NR;                               // 32 KB
    float* maxfd   = f_dst + NR;                               // 4 B (pad to 64)
    float* partial = maxfd + 64;                               // 256*128 = 128 KB

    hipMemsetAsync(maxfd, 0xFF, 4, stream);    // -NaN init for atomicMaxF
    k_proj<<<NR / 16, 256, 0, stream>>>(inSen, emb, W, a_src, a_dst, f_src, f_dst, maxfd, hB);
    k_fused<<<NR / 32, 1024, 0, stream>>>(adj, selfLink, f_src, f_dst, maxfd, hB, att, sent, partial);
    k_label<<<1, 128, 0, stream>>>(partial, cls_W, cls_b, pool, label);
}

// Round 13
// 582.034 us; speedup vs baseline: 1.0230x; 1.0230x over previous
//
#include <hip/hip_runtime.h>
#include <hip/hip_bf16.h>

#define NR 8192
#define WF 128
#define MSTRIDE 260   // mask LDS row stride in u32 (260%32=4 -> 2-way bank = free)

typedef short bf16x8 __attribute__((ext_vector_type(8)));
typedef float f32x4 __attribute__((ext_vector_type(4)));
typedef int   i32x4 __attribute__((ext_vector_type(4)));

static __device__ __forceinline__ unsigned int f2bf(float f) {
    unsigned int u = __float_as_uint(f);
    return (u + 0x7fffu + ((u >> 16) & 1u)) >> 16;
}
// works with *addr initialized to 0xFFFFFFFF (-NaN): int-max beats -1 for v>=0,
// uint-min beats UINT_MAX for v<0; mixed-sign interleavings keep the true max.
static __device__ __forceinline__ void atomicMaxF(float* addr, float v) {
    if (v >= 0.f) atomicMax((int*)addr, __float_as_int(v));
    else          atomicMin((unsigned int*)addr, __float_as_uint(v));
}
static __device__ __forceinline__ float lrelu(float x) { return x > 0.f ? x : 0.01f * x; }

// ---- k_proj: h = emb[inSen] @ W ; f_src/f_dst ; maxfd (atomic) ; hB (bf16 B-frags) ----
// hB layout: [colblk kb (256)][featgrp nf (8)][lane (64)][8 bf16]; lane = fx + 16*quad
// holds h^T[nf*16+fx][kb*32 + quad*8 + j], j=0..7.  Block = 16 rows (half a colblk).
__global__ __launch_bounds__(256) void k_proj(
    const int* __restrict__ inSen, const float* __restrict__ emb,
    const float* __restrict__ W, const float* __restrict__ a_src,
    const float* __restrict__ a_dst, float* __restrict__ f_src,
    float* __restrict__ f_dst, float* __restrict__ maxfd,
    unsigned short* __restrict__ hB)
{
    __shared__ float ht[16 * 132];
    const int t = threadIdx.x;
    const int f = t & 127, rh = t >> 7;     // feature, row-half (8 rows each)
    const int i0 = blockIdx.x * 16;

    int wd[8];
    #pragma unroll
    for (int r = 0; r < 8; ++r) wd[r] = inSen[i0 + rh * 8 + r];
    float h[8];
    #pragma unroll
    for (int r = 0; r < 8; ++r) h[r] = 0.f;

    for (int k4 = 0; k4 < 32; ++k4) {
        const float w0 = W[(k4 * 4 + 0) * WF + f];
        const float w1 = W[(k4 * 4 + 1) * WF + f];
        const float w2 = W[(k4 * 4 + 2) * WF + f];
        const float w3 = W[(k4 * 4 + 3) * WF + f];
        #pragma unroll
        for (int r = 0; r < 8; ++r) {
            float4 ev = ((const float4*)(emb + (size_t)wd[r] * 128))[k4];
            h[r] += ev.x * w0 + ev.y * w1 + ev.z * w2 + ev.w * w3;
        }
    }
    #pragma unroll
    for (int r = 0; r < 8; ++r) ht[(rh * 8 + r) * 132 + f] = h[r];
    __syncthreads();

    if (t < 16) {
        float s = 0.f, d = 0.f;
        for (int k4 = 0; k4 < 32; ++k4) {
            float4 hv = *(const float4*)(ht + t * 132 + k4 * 4);
            float4 as = ((const float4*)a_src)[k4];
            float4 ad = ((const float4*)a_dst)[k4];
            s += hv.x * as.x + hv.y * as.y + hv.z * as.z + hv.w * as.w;
            d += hv.x * ad.x + hv.y * ad.y + hv.z * ad.z + hv.w * ad.w;
        }
        f_src[i0 + t] = s;
        f_dst[i0 + t] = d;
        float dm = d;
        #pragma unroll
        for (int o = 1; o < 16; o <<= 1) dm = fmaxf(dm, __shfl_xor(dm, o));
        if (t == 0) atomicMaxF(maxfd, dm);
    }
    // hB fragment write: this block fills quads {half*2, half*2+1} of colblk kb
    {
        const int kb = blockIdx.x >> 1, half = blockIdx.x & 1;
        const int nf = t >> 5, l32 = t & 31;
        const int qloc = l32 >> 4, fx = l32 & 15;
        const int lane = (half * 2 + qloc) * 16 + fx;
        const float* hp = ht + (qloc * 8) * 132 + nf * 16 + fx;
        uint4 v;
        v.x = f2bf(hp[0 * 132]) | (f2bf(hp[1 * 132]) << 16);
        v.y = f2bf(hp[2 * 132]) | (f2bf(hp[3 * 132]) << 16);
        v.z = f2bf(hp[4 * 132]) | (f2bf(hp[5 * 132]) << 16);
        v.w = f2bf(hp[6 * 132]) | (f2bf(hp[7 * 132]) << 16);
        *(uint4*)(hB + ((size_t)kb * 8 + nf) * 512 + lane * 8) = v;
    }
}

// ---- adj chunk: 256 cols, lane owns 4 (i32x4, NT-loaded). Mask word -> mrow (LDS). ----
static __device__ __forceinline__ void adj_chunk(
    int c, i32x4 a, const float* __restrict__ fdl, int lane, int row, int sl,
    float fs, float C, int shl,
    unsigned int* __restrict__ mrow, float& sum)
{
    const float4 f = *(const float4*)(fdl + c * 256 + 4 * lane);
    const bool m0 = a[0] > 0, m1 = a[1] > 0, m2 = a[2] > 0, m3 = a[3] > 0;
    float p0 = m0 ? __expf(lrelu(fs + f.x) - C) : 0.f;
    float p1 = m1 ? __expf(lrelu(fs + f.y) - C) : 0.f;
    float p2 = m2 ? __expf(lrelu(fs + f.z) - C) : 0.f;
    float p3 = m3 ? __expf(lrelu(fs + f.w) - C) : 0.f;
    unsigned int nib = (m0 ? 1u : 0u) | (m1 ? 2u : 0u) | (m2 ? 4u : 0u) | (m3 ? 8u : 0u);
    float ssum = p0 + p1 + p2 + p3;
    if (c == (row >> 8)) {                      // wave-uniform: diagonal lives here
        if (lane == ((row & 255) >> 2)) {
            const int jd = row & 3;
            const int aj = jd == 0 ? a[0] : jd == 1 ? a[1] : jd == 2 ? a[2] : a[3];
            const float fj = jd == 0 ? f.x : jd == 1 ? f.y : jd == 2 ? f.z : f.w;
            const bool mo = aj > 0, mn = (aj + sl) > 0;
            if (mn != mo) {
                const float pd = __expf(lrelu(fs + fj) - C);
                if (mn) { nib |= 1u << jd; ssum += pd; }
                else    { nib &= ~(1u << jd); ssum -= pd; }
            }
        }
    }
    sum += ssum;
    // pack 8 lanes' nibbles -> one u32 mask word (bit = col%32), 8 words per 256-col chunk
    unsigned int v = nib << shl;
    v |= __shfl_xor(v, 1);
    v |= __shfl_xor(v, 2);
    v |= __shfl_xor(v, 4);
    if ((lane & 7) == 0) mrow[c * 8 + (lane >> 3)] = v;
}

#define NTL(p) __builtin_nontemporal_load((const i32x4*)(p))

// process one full adj row (32 chunks) with a pre-filled depth-8 register ring
static __device__ __forceinline__ float adj_row(
    const int* __restrict__ ap, const float* __restrict__ fdl,
    int lane, int row, int sl, float fs, float C, int shl,
    unsigned int* __restrict__ mrow,
    i32x4 a0, i32x4 a1, i32x4 a2, i32x4 a3, i32x4 a4, i32x4 a5, i32x4 a6, i32x4 a7)
{
    float sum = 0.f;
    #define ADJC(c, reg) adj_chunk((c), (reg), fdl, lane, row, sl, fs, C, shl, mrow, sum)
    #pragma unroll 1
    for (int g = 0; g < 24; g += 8) {
        ADJC(g + 0, a0); a0 = NTL(ap + (g +  8) * 256);
        ADJC(g + 1, a1); a1 = NTL(ap + (g +  9) * 256);
        ADJC(g + 2, a2); a2 = NTL(ap + (g + 10) * 256);
        ADJC(g + 3, a3); a3 = NTL(ap + (g + 11) * 256);
        ADJC(g + 4, a4); a4 = NTL(ap + (g + 12) * 256);
        ADJC(g + 5, a5); a5 = NTL(ap + (g + 13) * 256);
        ADJC(g + 6, a6); a6 = NTL(ap + (g + 14) * 256);
        ADJC(g + 7, a7); a7 = NTL(ap + (g + 15) * 256);
    }
    ADJC(24, a0); ADJC(25, a1); ADJC(26, a2); ADJC(27, a3);
    ADJC(28, a4); ADJC(29, a5); ADJC(30, a6); ADJC(31, a7);
    #undef ADJC
    return sum;
}

// ---- k_fused v8: EXACT round-9 structure (best measured: 583.8us total) with ONE
// change: phase-2 bf16 pack via v_cvt_pk (__float22bfloat162_rn; RNE == f2bf ->
// bit-identical output, ~30 fewer VALU ops/iter, VALUBusy drop verified in r12).
// TWO 16-row strips per 1024-thread block; wave pair (w, w+8) reads the SAME hB
// K-slice (halves hB re-read, second reader L1/L2-hot); adj loads NONTEMPORAL;
// separate 16KB sent tile (zeroed pre-phase-1; atomicAdd epilogue, no extra barrier).
__global__ __launch_bounds__(1024, 4) void k_fused(
    const int* __restrict__ adj, const int* __restrict__ slP,
    const float* __restrict__ f_src, const float* __restrict__ f_dst,
    const float* __restrict__ maxfd, const unsigned short* __restrict__ hB,
    float* __restrict__ att, float* __restrict__ sent, float* __restrict__ partial)
{
    __shared__ float fdl[NR];                       // 32 KB
    __shared__ unsigned int mask[32 * MSTRIDE];     // 33.3 KB
    __shared__ float tile[2][2048];                 // 16 KB (sent accumulators)
    __shared__ float sums[32];
    const int t = threadIdx.x, lane = t & 63, w = t >> 6;   // 16 waves
    const int i0 = blockIdx.x * 32;                          // 32 rows per block

    // issue row-A adj ring FIRST (HBM latency hides under fdl stage + barrier)
    const int rowA = i0 + 2 * w;
    const int* __restrict__ apA = adj + (size_t)rowA * NR + 4 * lane;
    i32x4 a0 = NTL(apA + 0 * 256);
    i32x4 a1 = NTL(apA + 1 * 256);
    i32x4 a2 = NTL(apA + 2 * 256);
    i32x4 a3 = NTL(apA + 3 * 256);
    i32x4 a4 = NTL(apA + 4 * 256);
    i32x4 a5 = NTL(apA + 5 * 256);
    i32x4 a6 = NTL(apA + 6 * 256);
    i32x4 a7 = NTL(apA + 7 * 256);

    #pragma unroll
    for (int i = 0; i < 2; ++i)
        *(float4*)(fdl + (i * 1024 + t) * 4) = *(const float4*)(f_dst + (i * 1024 + t) * 4);
    {   // zero sent tiles (4096 floats, 1 float4/thread)
        float4 z = make_float4(0.f, 0.f, 0.f, 0.f);
        *(float4*)(&tile[0][0] + t * 4) = z;
    }

    const int sl = slP[0];
    const float mfd = maxfd[0];
    const int shl = 4 * (lane & 7);
    __syncthreads();

    // ---- phase 1: this wave's two rows (local rows 2w, 2w+1) ----
    {
        const float fsA = f_src[rowA];
        const float CA = lrelu(fsA + mfd);
        float s = adj_row(apA, fdl, lane, rowA, sl, fsA, CA, shl,
                          mask + (2 * w) * MSTRIDE, a0, a1, a2, a3, a4, a5, a6, a7);
        #pragma unroll
        for (int o = 1; o < 64; o <<= 1) s += __shfl_xor(s, o);
        if (lane == 0) sums[2 * w] = 1.0f / s;
    }
    {
        const int rowB = rowA + 1;
        const int* __restrict__ apB = adj + (size_t)rowB * NR + 4 * lane;
        i32x4 b0 = NTL(apB + 0 * 256);
        i32x4 b1 = NTL(apB + 1 * 256);
        i32x4 b2 = NTL(apB + 2 * 256);
        i32x4 b3 = NTL(apB + 3 * 256);
        i32x4 b4 = NTL(apB + 4 * 256);
        i32x4 b5 = NTL(apB + 5 * 256);
        i32x4 b6 = NTL(apB + 6 * 256);
        i32x4 b7 = NTL(apB + 7 * 256);
        const float fsB = f_src[rowB];
        const float CB = lrelu(fsB + mfd);
        float s = adj_row(apB, fdl, lane, rowB, sl, fsB, CB, shl,
                          mask + (2 * w + 1) * MSTRIDE, b0, b1, b2, b3, b4, b5, b6, b7);
        #pragma unroll
        for (int o = 1; o < 64; o <<= 1) s += __shfl_xor(s, o);
        if (lane == 0) sums[2 * w + 1] = 1.0f / s;
    }
    __syncthreads();

    // ---- phase 2: waves 0-7 -> strip 0, waves 8-15 -> strip 1; wave pair (w, w+8)
    // shares the same hB K-slice. Inner loop = round-5 measured-best structure.
    const int ss = w >> 3, wk = w & 7;
    const int fx = lane & 15, quad = lane >> 4;
    const int lrow = ss * 16 + fx;
    const int row = i0 + lrow;
    const float fs = f_src[row];
    const float C = lrelu(fs + mfd);
    const float il = sums[lrow];
    float* __restrict__ ar = att + (size_t)row * NR;
    const unsigned int* __restrict__ mrow = mask + lrow * MSTRIDE;
    f32x4 acc[8] = {};
    const int k0 = wk * 1024;

    for (int kk4 = k0; kk4 < k0 + 1024; kk4 += 128) {
        const uint4 mw = *(const uint4*)(mrow + (kk4 >> 5));     // LDS
        const unsigned int mwa[4] = {mw.x, mw.y, mw.z, mw.w};
        #pragma unroll
        for (int j4 = 0; j4 < 4; ++j4) {
            const int kk = kk4 + j4 * 32;
            const int kb = kk >> 5;
            const unsigned short* hp = hB + (size_t)kb * 4096 + lane * 8;
            bf16x8 bfr[8];
            #pragma unroll
            for (int nf = 0; nf < 8; ++nf) bfr[nf] = *(const bf16x8*)(hp + nf * 512);

            const unsigned int mbyte = (mwa[j4] >> (quad * 8)) & 0xffu;
            const float4 fd0 = *(const float4*)(fdl + kk + quad * 8);     // LDS broadcast
            const float4 fd1 = *(const float4*)(fdl + kk + quad * 8 + 4);
            const float fv[8] = {fd0.x, fd0.y, fd0.z, fd0.w, fd1.x, fd1.y, fd1.z, fd1.w};
            float p[8];
            #pragma unroll
            for (int j = 0; j < 8; ++j)
                p[j] = ((mbyte >> j) & 1u) ? __expf(lrelu(fs + fv[j]) - C) : 0.f;

            const float4 w0 = make_float4(p[0] * il, p[1] * il, p[2] * il, p[3] * il);
            const float4 w1 = make_float4(p[4] * il, p[5] * il, p[6] * il, p[7] * il);
            *(float4*)(ar + kk + quad * 8) = w0;
            *(float4*)(ar + kk + quad * 8 + 4) = w1;

            union { __hip_bfloat162 h2[4]; bf16x8 v; } cv;
            #pragma unroll
            for (int j = 0; j < 4; ++j)
                cv.h2[j] = __float22bfloat162_rn(make_float2(p[2 * j], p[2 * j + 1]));
            #pragma unroll
            for (int nf = 0; nf < 8; ++nf)
                acc[nf] = __builtin_amdgcn_mfma_f32_16x16x32_bf16(cv.v, bfr[nf], acc[nf], 0, 0, 0);
        }
    }
    // ---- epilogue: ds-atomic reduce into tile (no alias with fdl/mask -> no barrier
    // needed before; tiles were zeroed pre-phase-1 barrier) ----
    // D layout (16x16x32): row = quad*4+reg, col = nf*16+fx
    #pragma unroll
    for (int reg = 0; reg < 4; ++reg) {
        #pragma unroll
        for (int nf = 0; nf < 8; ++nf)
            atomicAdd(&tile[ss][(quad * 4 + reg) * 128 + nf * 16 + fx], acc[nf][reg]);
    }
    __syncthreads();
    {   // sent: 4096 floats, 1 float4/thread, scaled by invl
        const int e = t * 4;
        const int st2 = e >> 11, off = e & 2047, r = off >> 7, f0 = off & 127;
        const float vin = sums[st2 * 16 + r];
        const float* tf = &tile[0][0];
        float4 vv = make_float4(tf[e] * vin, tf[e + 1] * vin, tf[e + 2] * vin, tf[e + 3] * vin);
        *(float4*)(sent + (size_t)(i0 + st2 * 16 + r) * WF + f0) = vv;
    }
    if (t < 128) {                            // column max over the block's 32 rows
        float mx = -1e30f;
        #pragma unroll
        for (int s = 0; s < 2; ++s)
            for (int r = 0; r < 16; ++r)
                mx = fmaxf(mx, tile[s][r * 128 + t] * sums[s * 16 + r]);
        partial[blockIdx.x * 128 + t] = mx;
    }
}

// ---- k_label: final pool max (256 block partials) + classifier ------------------------
__global__ __launch_bounds__(128) void k_label(
    const float* __restrict__ partial, const float* __restrict__ cls_W,
    const float* __restrict__ cls_b, float* __restrict__ pool,
    float* __restrict__ label)
{
    __shared__ float s0[128], s1[128];
    const int t = threadIdx.x;
    float m0 = -1e30f, m1 = -1e30f, m2 = -1e30f, m3 = -1e30f;
    for (int b = 0; b < 256; b += 4) {
        m0 = fmaxf(m0, partial[(b + 0) * 128 + t]);
        m1 = fmaxf(m1, partial[(b + 1) * 128 + t]);
        m2 = fmaxf(m2, partial[(b + 2) * 128 + t]);
        m3 = fmaxf(m3, partial[(b + 3) * 128 + t]);
    }
    const float m = fmaxf(fmaxf(m0, m1), fmaxf(m2, m3));
    pool[t] = m;
    s0[t] = m * cls_W[t * 2 + 0];
    s1[t] = m * cls_W[t * 2 + 1];
    __syncthreads();
    if (t == 0) {
        float z0 = cls_b[0], z1 = cls_b[1];
        for (int f = 0; f < 128; ++f) { z0 += s0[f]; z1 += s1[f]; }
        float mm = fmaxf(z0, z1);
        float e0 = __expf(z0 - mm), e1 = __expf(z1 - mm);
        float inv = 1.0f / (e0 + e1);
        label[0] = e0 * inv;
        label[1] = e1 * inv;
    }
}

extern "C" void kernel_launch(void* const* d_in, const int* in_sizes, int n_in,
                              void* d_out, int out_size, void* d_ws, size_t ws_size,
                              hipStream_t stream)
{
    const int*   inSen    = (const int*)d_in[0];
    const int*   adj      = (const int*)d_in[1];
    const int*   selfLink = (const int*)d_in[2];
    const float* emb      = (const float*)d_in[3];
    const float* W        = (const float*)d_in[4];
    const float* a_src    = (const float*)d_in[5];
    const float* a_dst    = (const float*)d_in[6];
    const float* cls_W    = (const float*)d_in[7];
    const float* cls_b    = (const float*)d_in[8];

    float* out   = (float*)d_out;
    float* pool  = out;                         // 128
    float* att   = out + 128;                   // 8192*8192
    float* sent  = att + (size_t)NR * NR;       // 8192*128
    float* label = sent + (size_t)NR * WF;      // 2

    char* ws = (char*)d_ws;
    unsigned short* hB    = (unsigned short*)ws;               // 2 MB
    float* f_src   = (float*)(ws + (2u << 20));                // 32 KB
    float* f_dst   = f_src + NR;                               // 32 KB
    float* maxfd   = f_dst + NR;                               // 4 B (pad to 64)
    float* partial = maxfd + 64;                               // 256*128 = 128 KB

    hipMemsetAsync(maxfd, 0xFF, 4, stream);    // -NaN init for atomicMaxF
    k_proj<<<NR / 16, 256, 0, stream>>>(inSen, emb, W, a_src, a_dst, f_src, f_dst, maxfd, hB);
    k_fused<<<NR / 32, 1024, 0, stream>>>(adj, selfLink, f_src, f_dst, maxfd, hB, att, sent, partial);
    k_label<<<1, 128, 0, stream>>>(partial, cls_W, cls_b, pool, label);
}